// Round 3
// baseline (217.847 us; speedup 1.0000x reference)
//
#include <hip/hip_runtime.h>
#include <hip/hip_bf16.h>
#include <cstdint>
#include <cstddef>

#define DEV static __device__ __forceinline__

typedef float f32x4 __attribute__((ext_vector_type(4)));
typedef __bf16 bf16x8 __attribute__((ext_vector_type(8)));
typedef unsigned int u32x4 __attribute__((ext_vector_type(4)));
typedef unsigned short us4v __attribute__((ext_vector_type(4)));

static constexpr int BATCH  = 4;
static constexpr int SEQ    = 4096;
static constexpr int DMODEL = 1024;
static constexpr int DHEAD  = 64;

// ws layout (bytes):
//   WT  bf16 [3][64][1024]            @ 0        (393216)
//   Q   bf16 [B][S][64] (pre-scaled)  @ 393216   (2097152)
//   K   bf16 [B][S][64]               @ 2490368  (2097152)
//   VT  bf16 [B][64][S]               @ 4587520  (2097152)
static constexpr size_t WT_OFF = 0;
static constexpr size_t Q_OFF  = 393216;
static constexpr size_t K_OFF  = Q_OFF + 2097152;
static constexpr size_t VT_OFF = K_OFF + 2097152;

DEV unsigned short f2bf_bits(float f) {
    union { float f; unsigned u; } v; v.f = f;
    unsigned r = (v.u + 0x7fffu + ((v.u >> 16) & 1u)) >> 16;
    return (unsigned short)r;
}
DEV __bf16 f2bf(float f) {
    union { unsigned short s; __bf16 b; } o; o.s = f2bf_bits(f); return o.b;
}
DEV bf16x8 load_bf16x8(const unsigned short* p) {
    union { u32x4 u; bf16x8 b; } t;
    t.u = *(const u32x4*)p;
    return t.b;
}
DEV unsigned cvt_pk_bf16(float lo, float hi) {
    unsigned r;
    asm("v_cvt_pk_bf16_f32 %0, %1, %2" : "=v"(r) : "v"(lo), "v"(hi));
    return r;
}

// ---------------- kernel 0: W fp32 -> WT bf16 [3][64][1024] ----------------
__global__ __launch_bounds__(256) void wtrans_kernel(
        const float* __restrict__ Wq, const float* __restrict__ Wk,
        const float* __restrict__ Wv, unsigned short* __restrict__ WT) {
    int idx = blockIdx.x * 256 + threadIdx.x;     // 3*64*1024 = 196608 total
    int m = idx >> 16;
    int r = idx & 65535;
    int d = r >> 10, k = r & 1023;
    const float* W = (m == 0) ? Wq : ((m == 1) ? Wk : Wv);
    WT[idx] = f2bf_bits(W[k * DHEAD + d]);
}

// ---------------- kernel 1: fused QKV projection, split-K x4 ----------------
// grid 1024 x 256 threads. Block = one 16-row tile; wave w owns K-quarter w.
__global__ __launch_bounds__(256, 4) void proj_kernel(
        const float* __restrict__ x, const unsigned short* __restrict__ WT,
        unsigned short* __restrict__ Qs, unsigned short* __restrict__ Kd,
        unsigned short* __restrict__ VT) {
    __shared__ float plds[3 * 12 * 256];          // 36 KiB partials (waves 1..3)
    const int wave = threadIdx.x >> 6;
    const int lane = threadIdx.x & 63;
    const int lr = lane & 15, lg = lane >> 4;
    const int rowbase = blockIdx.x * 16;

    const float* xrow = x + (size_t)(rowbase + lr) * DMODEL + wave * 256;
    const unsigned short* WTh = WT + wave * 256;

    f32x4 acc[3][4];
#pragma unroll
    for (int m = 0; m < 3; ++m)
#pragma unroll
        for (int t = 0; t < 4; ++t) acc[m][t] = (f32x4){0.f, 0.f, 0.f, 0.f};

    for (int k0 = 0; k0 < 256; k0 += 32) {
        const float* ap = xrow + k0 + lg * 8;
        f32x4 a0 = *(const f32x4*)ap;
        f32x4 a1 = *(const f32x4*)(ap + 4);
        bf16x8 af;
        af[0] = f2bf(a0[0]); af[1] = f2bf(a0[1]); af[2] = f2bf(a0[2]); af[3] = f2bf(a0[3]);
        af[4] = f2bf(a1[0]); af[5] = f2bf(a1[1]); af[6] = f2bf(a1[2]); af[7] = f2bf(a1[3]);
#pragma unroll
        for (int m = 0; m < 3; ++m) {
#pragma unroll
            for (int t = 0; t < 4; ++t) {
                bf16x8 bf = load_bf16x8(WTh + (size_t)(m * 64 + t * 16 + lr) * DMODEL + k0 + lg * 8);
                acc[m][t] = __builtin_amdgcn_mfma_f32_16x16x32_bf16(af, bf, acc[m][t], 0, 0, 0);
            }
        }
    }

    if (wave != 0) {
        float* pl = plds + (wave - 1) * (12 * 256);
#pragma unroll
        for (int m = 0; m < 3; ++m)
#pragma unroll
            for (int t = 0; t < 4; ++t)
                *(f32x4*)(pl + ((m * 4 + t) * 64 + lane) * 4) = acc[m][t];
    }
    __syncthreads();
    if (wave == 0) {
#pragma unroll
        for (int w = 0; w < 3; ++w) {
            const float* pl = plds + w * (12 * 256);
#pragma unroll
            for (int m = 0; m < 3; ++m)
#pragma unroll
                for (int t = 0; t < 4; ++t)
                    acc[m][t] += *(const f32x4*)(pl + ((m * 4 + t) * 64 + lane) * 4);
        }

        // fold 1/sqrt(64) * log2(e) into Q so attention softmax can use exp2
        const float QSCALE = 0.18033688011112042f;
        const int b = rowbase >> 12;
        const int srow = rowbase & 4095;
#pragma unroll
        for (int t = 0; t < 4; ++t) {
            us4v vv;
#pragma unroll
            for (int e = 0; e < 4; ++e) {
                int r = rowbase + lg * 4 + e;
                int d = t * 16 + lr;
                Qs[(size_t)r * DHEAD + d] = f2bf_bits(acc[0][t][e] * QSCALE);
                Kd[(size_t)r * DHEAD + d] = f2bf_bits(acc[1][t][e]);
                vv[e] = f2bf_bits(acc[2][t][e]);
            }
            *(us4v*)(VT + ((size_t)b * DHEAD + t * 16 + lr) * SEQ + srow + lg * 4) = vv;
        }
    }
}

// ---------------- kernel 2: causal flash attention ----------------
// grid 1024 x 256 threads (4 waves). Block = one 16-row q-group; the 4
// waves split the KV range (64-key blocks, j % 4 == wave) and merge via LDS.
// Swapped QK^T: lane holds a full P-row (q = lane&15), m/l are scalars.
__global__ __launch_bounds__(256, 4) void attn_kernel(
        const unsigned short* __restrict__ Qs, const unsigned short* __restrict__ Kd,
        const unsigned short* __restrict__ VT, float* __restrict__ out) {
    __shared__ unsigned short plds[4][16 * 88];   // per-wave P buffer, stride 88 bf16
    __shared__ float olds[3][16 * 68];            // waves 1..3 O partials
    __shared__ float mlds[3][16], llds[3][16];

    const int wave = threadIdx.x >> 6;
    const int lane = threadIdx.x & 63;
    const int lr = lane & 15, lg = lane >> 4;

    const int b = blockIdx.x & 3;
    const int g = 255 - (blockIdx.x >> 2);        // longest q-groups first
    const int qbase = g * 16;
    const int qabs = qbase + lr;

    const unsigned short* Qb = Qs + (size_t)b * SEQ * DHEAD;
    const unsigned short* Kb = Kd + (size_t)b * SEQ * DHEAD;
    const unsigned short* Vb = VT + (size_t)b * DHEAD * SEQ;

    const bf16x8 qf0 = load_bf16x8(Qb + (size_t)qabs * DHEAD + lg * 8);
    const bf16x8 qf1 = load_bf16x8(Qb + (size_t)qabs * DHEAD + 32 + lg * 8);

    f32x4 o[4];
#pragma unroll
    for (int t = 0; t < 4; ++t) o[t] = (f32x4){0.f, 0.f, 0.f, 0.f};
    float m = -1e30f, l = 0.f;

    unsigned* pwd = (unsigned*)plds[wave];
    const unsigned short* prd = plds[wave];

    const int nblk = (qbase + 16 + 63) >> 6;      // 64-key blocks covering [0, qbase+16)
    for (int j = wave; j < nblk; j += 4) {
        const int kv0 = j << 6;

        bf16x8 kf[4][2];
#pragma unroll
        for (int kb = 0; kb < 4; ++kb)
#pragma unroll
            for (int h = 0; h < 2; ++h)
                kf[kb][h] = load_bf16x8(Kb + (size_t)(kv0 + kb * 16 + lr) * DHEAD + h * 32 + lg * 8);
        bf16x8 vf[2][4];
#pragma unroll
        for (int c = 0; c < 2; ++c)
#pragma unroll
            for (int t = 0; t < 4; ++t)
                vf[c][t] = load_bf16x8(Vb + (size_t)(t * 16 + lr) * SEQ + kv0 + c * 32 + lg * 8);

        // S^T = K . Q^T : lane (lr,lg) holds S[k=kv0+16kb+4lg+e][q=qbase+lr]
        f32x4 sf[4];
#pragma unroll
        for (int kb = 0; kb < 4; ++kb) {
            f32x4 z = (f32x4){0.f, 0.f, 0.f, 0.f};
            z = __builtin_amdgcn_mfma_f32_16x16x32_bf16(kf[kb][0], qf0, z, 0, 0, 0);
            z = __builtin_amdgcn_mfma_f32_16x16x32_bf16(kf[kb][1], qf1, z, 0, 0, 0);
            sf[kb] = z;
        }

        if (kv0 + 63 > qbase) {                   // causal mask (wave-uniform branch)
#pragma unroll
            for (int kb = 0; kb < 4; ++kb)
#pragma unroll
                for (int e = 0; e < 4; ++e) {
                    int kabs = kv0 + kb * 16 + lg * 4 + e;
                    if (kabs > qabs) sf[kb][e] = -1e30f;
                }
        }

        // row max: 15 in-lane + 2 shfl (lanes {lr, lr+16, lr+32, lr+48})
        float mb;
#pragma unroll
        for (int kb = 0; kb < 4; ++kb) {
            float t0 = fmaxf(fmaxf(sf[kb][0], sf[kb][1]), fmaxf(sf[kb][2], sf[kb][3]));
            mb = (kb == 0) ? t0 : fmaxf(mb, t0);
        }
        mb = fmaxf(mb, __shfl_xor(mb, 16));
        mb = fmaxf(mb, __shfl_xor(mb, 32));

        if (__any(mb > m)) {                      // defer-max: skip rescale if no growth
            float mn = fmaxf(m, mb);
            float sc = exp2f(m - mn);
            m = mn;
            l *= sc;
#pragma unroll
            for (int e = 0; e < 4; ++e) {
                float sce = __shfl(sc, (lane & 48) | (lg * 4 + e));
#pragma unroll
                for (int t = 0; t < 4; ++t) o[t][e] *= sce;
            }
        }

        float s = 0.f;
#pragma unroll
        for (int kb = 0; kb < 4; ++kb)
#pragma unroll
            for (int e = 0; e < 4; ++e) {
                float pv = exp2f(sf[kb][e] - m);
                sf[kb][e] = pv;
                s += pv;
            }
        s += __shfl_xor(s, 16);
        s += __shfl_xor(s, 32);
        l += s;

        // pack P to bf16 pairs, transpose through wave-local LDS
#pragma unroll
        for (int kb = 0; kb < 4; ++kb)
#pragma unroll
            for (int ps = 0; ps < 2; ++ps)
                pwd[lr * 44 + kb * 8 + lg * 2 + ps] =
                    cvt_pk_bf16(sf[kb][2 * ps], sf[kb][2 * ps + 1]);

        asm volatile("s_waitcnt lgkmcnt(0)" ::: "memory");
        __builtin_amdgcn_sched_barrier(0);

        bf16x8 pa0 = load_bf16x8(prd + lr * 88 + lg * 8);
        bf16x8 pa1 = load_bf16x8(prd + lr * 88 + 32 + lg * 8);
#pragma unroll
        for (int t = 0; t < 4; ++t) {
            o[t] = __builtin_amdgcn_mfma_f32_16x16x32_bf16(pa0, vf[0][t], o[t], 0, 0, 0);
            o[t] = __builtin_amdgcn_mfma_f32_16x16x32_bf16(pa1, vf[1][t], o[t], 0, 0, 0);
        }
    }

    // merge the 4 waves' partials (m, l, o)
    if (wave != 0) {
#pragma unroll
        for (int t = 0; t < 4; ++t)
#pragma unroll
            for (int e = 0; e < 4; ++e)
                olds[wave - 1][(lg * 4 + e) * 68 + t * 16 + lr] = o[t][e];
        if (lg == 0) { mlds[wave - 1][lr] = m; llds[wave - 1][lr] = l; }
    }
    __syncthreads();
    if (wave == 0) {
        float mw[3], lw[3];
        float ms = m;
#pragma unroll
        for (int w = 0; w < 3; ++w) {
            mw[w] = mlds[w][lr]; lw[w] = llds[w][lr];
            ms = fmaxf(ms, mw[w]);
        }
        float a0 = exp2f(m - ms);
        float aw[3];
        float L = a0 * l;
#pragma unroll
        for (int w = 0; w < 3; ++w) { aw[w] = exp2f(mw[w] - ms); L += aw[w] * lw[w]; }
        float inv = 1.f / L;
        a0 *= inv;
#pragma unroll
        for (int w = 0; w < 3; ++w) aw[w] *= inv;

        float* ob = out + ((size_t)b * SEQ + qbase) * DHEAD;
#pragma unroll
        for (int e = 0; e < 4; ++e) {
            int src = (lane & 48) | (lg * 4 + e);
            float A0 = __shfl(a0, src);
            float A1 = __shfl(aw[0], src);
            float A2 = __shfl(aw[1], src);
            float A3 = __shfl(aw[2], src);
#pragma unroll
            for (int t = 0; t < 4; ++t) {
                float v = o[t][e] * A0
                        + olds[0][(lg * 4 + e) * 68 + t * 16 + lr] * A1
                        + olds[1][(lg * 4 + e) * 68 + t * 16 + lr] * A2
                        + olds[2][(lg * 4 + e) * 68 + t * 16 + lr] * A3;
                ob[(size_t)(lg * 4 + e) * DHEAD + t * 16 + lr] = v;
            }
        }
    }
}

extern "C" void kernel_launch(void* const* d_in, const int* in_sizes, int n_in,
                              void* d_out, int out_size, void* d_ws, size_t ws_size,
                              hipStream_t stream) {
    const float* x  = (const float*)d_in[0];
    const float* Wq = (const float*)d_in[1];
    const float* Wk = (const float*)d_in[2];
    const float* Wv = (const float*)d_in[3];
    float* out = (float*)d_out;

    char* ws = (char*)d_ws;
    unsigned short* WT = (unsigned short*)(ws + WT_OFF);
    unsigned short* Q  = (unsigned short*)(ws + Q_OFF);
    unsigned short* K  = (unsigned short*)(ws + K_OFF);
    unsigned short* VT = (unsigned short*)(ws + VT_OFF);

    hipLaunchKernelGGL(wtrans_kernel, dim3(768),  dim3(256), 0, stream, Wq, Wk, Wv, WT);
    hipLaunchKernelGGL(proj_kernel,   dim3(1024), dim3(256), 0, stream, x, WT, Q, K, VT);
    hipLaunchKernelGGL(attn_kernel,   dim3(1024), dim3(256), 0, stream, Q, K, VT, out);
}

// Round 6
// 176.922 us; speedup vs baseline: 1.2313x; 1.2313x over previous
//
#include <hip/hip_runtime.h>
#include <hip/hip_bf16.h>
#include <cstdint>
#include <cstddef>

#define DEV static __device__ __forceinline__

typedef float f32x4 __attribute__((ext_vector_type(4)));
typedef __bf16 bf16x8 __attribute__((ext_vector_type(8)));
typedef unsigned int u32x4 __attribute__((ext_vector_type(4)));
typedef unsigned int u32x2 __attribute__((ext_vector_type(2)));
typedef unsigned short us4v __attribute__((ext_vector_type(4)));

static constexpr int BATCH  = 4;
static constexpr int SEQ    = 4096;
static constexpr int DMODEL = 1024;
static constexpr int DHEAD  = 64;

// ws layout (bytes):
//   WTf bf16 [32 ktile][12 frag][64 lane][8]  @ 0        (393216)
//   Q   bf16 [B][S][64] (pre-scaled)          @ 393216   (2097152)
//   K   bf16 [B][S][64]                       @ 2490368  (2097152)
//   VT  bf16 [B][64][S]                       @ 4587520  (2097152)
static constexpr size_t WT_OFF = 0;
static constexpr size_t Q_OFF  = 393216;
static constexpr size_t K_OFF  = Q_OFF + 2097152;
static constexpr size_t VT_OFF = K_OFF + 2097152;

DEV unsigned short f2bf_bits(float f) {
    union { float f; unsigned u; } v; v.f = f;
    unsigned r = (v.u + 0x7fffu + ((v.u >> 16) & 1u)) >> 16;
    return (unsigned short)r;
}
DEV bf16x8 load_bf16x8(const unsigned short* p) {
    union { u32x4 u; bf16x8 b; } t;
    t.u = *(const u32x4*)p;
    return t.b;
}
DEV unsigned cvt_pk_bf16(float lo, float hi) {
    unsigned r;
    asm("v_cvt_pk_bf16_f32 %0, %1, %2" : "=v"(r) : "v"(lo), "v"(hi));
    return r;
}
// async global->LDS, 16B per lane; lds dest = wave-uniform base + lane*16
DEV void gl_lds16(const void* g, void* l) {
    __builtin_amdgcn_global_load_lds(
        (const __attribute__((address_space(1))) unsigned int*)g,
        (__attribute__((address_space(3))) unsigned int*)l, 16, 0, 0);
}

// ---------------- kernel 0: W fp32 -> WTf (fragment-linear bf16) ----------------
// WTf[kt][f][lane][e] = W_m[kt*32 + (lane>>4)*8 + e][ (f*16 + (lane&15)) & 63 ],
// m = (f*16 + (lane&15)) >> 6.  24576 threads x 8 elems.
__global__ __launch_bounds__(256) void wtrans_kernel(
        const float* __restrict__ Wq, const float* __restrict__ Wk,
        const float* __restrict__ Wv, unsigned short* __restrict__ WTf) {
    int idx = blockIdx.x * 256 + threadIdx.x;     // 0..24575
    int kt = idx / 768;
    int rem = idx - kt * 768;
    int f = rem >> 6, lane = rem & 63;
    int c = f * 16 + (lane & 15);
    int m = c >> 6, d = c & 63;
    int k0 = kt * 32 + (lane >> 4) * 8;
    const float* W = (m == 0) ? Wq : ((m == 1) ? Wk : Wv);
    unsigned short v[8];
#pragma unroll
    for (int e = 0; e < 8; ++e) v[e] = f2bf_bits(W[(size_t)(k0 + e) * DHEAD + d]);
    u32x4 o;
#pragma unroll
    for (int j = 0; j < 4; ++j) o[j] = (unsigned)v[2 * j] | ((unsigned)v[2 * j + 1] << 16);
    *(u32x4*)&WTf[(size_t)idx * 8] = o;
}

// ---------------- kernel 1: fused QKV projection ----------------
// grid 512 x 256 thr (4 waves). Block = 32 rows x 192 cols; wave (rh,ch) owns
// 16 rows x 96 cols. x staged f32->bf16 in LDS (stride 36), WTf via gl_lds.
__global__ __launch_bounds__(256, 2) void proj_kernel(
        const float* __restrict__ x, const unsigned short* __restrict__ WTf,
        unsigned short* __restrict__ Qs, unsigned short* __restrict__ Kd,
        unsigned short* __restrict__ VT) {
    __shared__ unsigned short xb[2][32][36];      // 4.6 KiB
    __shared__ unsigned short wt[2][6144];        // 2 x 12 KiB, frag-linear
    const int tid = threadIdx.x;
    const int w = tid >> 6, lane = tid & 63;
    const int lr = lane & 15, lg = lane >> 4;
    const int rh = w >> 1, ch = w & 1;
    const int rowbase = blockIdx.x * 32;
    const int xrow = tid >> 3, xcg = tid & 7;

    const float* xsrc = x + (size_t)(rowbase + xrow) * DMODEL + xcg * 4;

    f32x4 xr = *(const f32x4*)xsrc;               // k-step 0
#pragma unroll
    for (int c = 0; c < 3; ++c)                   // stage wt(0) -> buf0
        gl_lds16(WTf + (size_t)(c * 256 + w * 64 + lane) * 8,
                 &wt[0][(c * 256 + w * 64) * 8]);

    f32x4 acc[6];
#pragma unroll
    for (int f6 = 0; f6 < 6; ++f6) acc[f6] = (f32x4){0.f, 0.f, 0.f, 0.f};

    for (int k = 0; k < 32; ++k) {
        const int buf = k & 1;
        __syncthreads();                          // compute(k-1) done everywhere
        // write x(k) bf16 into LDS
        u32x2 xp;
        xp[0] = cvt_pk_bf16(xr[0], xr[1]);
        xp[1] = cvt_pk_bf16(xr[2], xr[3]);
        *(u32x2*)&xb[buf][xrow][xcg * 4] = xp;
        if (k < 31) {
#pragma unroll
            for (int c = 0; c < 3; ++c)           // stage wt(k+1) -> other buf
                gl_lds16(WTf + (size_t)(k + 1) * 6144 + (size_t)(c * 256 + w * 64 + lane) * 8,
                         &wt[buf ^ 1][(c * 256 + w * 64) * 8]);
            xr = *(const f32x4*)(xsrc + (k + 1) * 32);
            asm volatile("s_waitcnt vmcnt(4)" ::: "memory");   // wt(k) landed
        } else {
            asm volatile("s_waitcnt vmcnt(0)" ::: "memory");
        }
        __syncthreads();                          // staged k visible to all

        bf16x8 af = load_bf16x8(&xb[buf][rh * 16 + lr][lg * 8]);
#pragma unroll
        for (int f6 = 0; f6 < 6; ++f6) {
            bf16x8 bf = load_bf16x8(&wt[buf][(ch * 6 + f6) * 512 + lane * 8]);
            acc[f6] = __builtin_amdgcn_mfma_f32_16x16x32_bf16(af, bf, acc[f6], 0, 0, 0);
        }
    }

    // epilogue: cols c = (ch*6+f6)*16 + lr -> (m = c>>6, d = c&63)
    const float QSCALE = 0.18033688011112042f;    // 2^-3 * log2(e) folded for exp2
    const int b = rowbase >> 12;
    const int srow0 = (rowbase & 4095) + rh * 16 + lg * 4;
#pragma unroll
    for (int f6 = 0; f6 < 6; ++f6) {
        int c = (ch * 6 + f6) * 16 + lr;
        int m = c >> 6, d = c & 63;
        if (m == 2) {
            us4v vv;
#pragma unroll
            for (int e = 0; e < 4; ++e) vv[e] = f2bf_bits(acc[f6][e]);
            *(us4v*)&VT[((size_t)b * DHEAD + d) * SEQ + srow0] = vv;
        } else {
#pragma unroll
            for (int e = 0; e < 4; ++e) {
                size_t r = (size_t)rowbase + rh * 16 + lg * 4 + e;
                if (m == 0) Qs[r * DHEAD + d] = f2bf_bits(acc[f6][e] * QSCALE);
                else        Kd[r * DHEAD + d] = f2bf_bits(acc[f6][e]);
            }
        }
    }
}

// ---------------- kernel 2: causal flash attention ----------------
// grid 512 x 256 thr (4 waves). Block = 2 q-groups (qt) x 2-way kv split (p).
// K/V tiles staged coalesced via gl_lds (XOR-swizzled), double-buffered.
__global__ __launch_bounds__(256, 2) void attn_kernel(
        const unsigned short* __restrict__ Qs, const unsigned short* __restrict__ Kd,
        const unsigned short* __restrict__ VT, float* __restrict__ out) {
    __shared__ __align__(16) unsigned char smem[65536 + 11264];
    // smem[0..65536): [buf][tile(2)][ K 8192 | V 8192 ]; P-lds at 65536 + w*2816.
    const int tid = threadIdx.x;
    const int w = tid >> 6, lane = tid & 63;
    const int lr = lane & 15, lg = lane >> 4;
    const int p = w & 1, qt = w >> 1;

    const int b = blockIdx.x & 3;
    const int qpair = 127 - (blockIdx.x >> 2);    // longest first
    const int qbase = qpair * 32 + qt * 16;
    const int kv_end = qbase + 16;
    const int nt = (qpair * 32 + 95) >> 6;        // kv tiles covering the pair
    const int nsteps = (nt + 1) >> 1;

    const unsigned short* Qb = Qs + (size_t)b * SEQ * DHEAD;
    const unsigned short* Kb = Kd + (size_t)b * SEQ * DHEAD;
    const unsigned short* Vb = VT + (size_t)b * DHEAD * SEQ;

    const bf16x8 qf0 = load_bf16x8(Qb + (size_t)(qbase + lr) * DHEAD + lg * 8);
    const bf16x8 qf1 = load_bf16x8(Qb + (size_t)(qbase + lr) * DHEAD + 32 + lg * 8);

    f32x4 o[4];
#pragma unroll
    for (int t = 0; t < 4; ++t) o[t] = (f32x4){0.f, 0.f, 0.f, 0.f};
    float m = -1e30f, l = 0.f;

    unsigned short* pl = (unsigned short*)(smem + 65536 + w * 2816);
    unsigned* pwd = (unsigned*)pl;

    // stage both tiles {2s, 2s+1} of step s into buf (32 KiB, 8 chunks/thread)
    auto STAGE = [&](int s, int buf) {
#pragma unroll
        for (int c = 0; c < 8; ++c) {
            int g = (c * 4 + w) * 64 + lane;      // chunk id 0..2047
            int tile = g >> 10;                   // uniform per (c,w)
            int kv0 = s * 128 + tile * 64;
            int r10 = g & 1023;
            const unsigned short* src;
            if (r10 < 512) {                      // K region
                int row = r10 >> 3, ccl = r10 & 7;
                src = Kb + (size_t)(kv0 + row) * DHEAD + ((ccl ^ (row & 7)) * 8);
            } else {                              // V region
                int r9 = r10 & 511;
                int d = r9 >> 3, ccl = r9 & 7;
                src = Vb + (size_t)d * SEQ + kv0 + ((ccl ^ (d & 7)) * 8);
            }
            gl_lds16(src, smem + buf * 32768 + ((c * 4 + w) * 64) * 16);
        }
    };

    STAGE(0, 0);
    for (int s = 0; s < nsteps; ++s) {
        const int buf = s & 1;
        __syncthreads();                          // compute(s-1) done: safe to overwrite
        if (s + 1 < nsteps) {
            STAGE(s + 1, buf ^ 1);
            asm volatile("s_waitcnt vmcnt(8)" ::: "memory");   // step-s tiles landed
        } else {
            asm volatile("s_waitcnt vmcnt(0)" ::: "memory");
        }
        __syncthreads();

        const int ti = 2 * s + p;
        const int kv0 = ti * 64;
        if (kv0 < kv_end) {
            const unsigned char* Kt = smem + buf * 32768 + (ti & 1) * 16384;
            const unsigned char* Vt = Kt + 8192;

            bf16x8 kf[4][2];
#pragma unroll
            for (int kb = 0; kb < 4; ++kb)
#pragma unroll
                for (int h = 0; h < 2; ++h)
                    kf[kb][h] = load_bf16x8((const unsigned short*)(
                        Kt + (kb * 16 + lr) * 128 + (((h * 4 + lg) ^ (lr & 7)) * 16)));
            bf16x8 vf[2][4];
#pragma unroll
            for (int c2 = 0; c2 < 2; ++c2)
#pragma unroll
                for (int t = 0; t < 4; ++t)
                    vf[c2][t] = load_bf16x8((const unsigned short*)(
                        Vt + (t * 16 + lr) * 128 + (((c2 * 4 + lg) ^ (lr & 7)) * 16)));

            // S^T = K . Q^T : lane holds S[k = kv0+16kb+4lg+e][q = qbase+lr]
            f32x4 sf[4];
#pragma unroll
            for (int kb = 0; kb < 4; ++kb) {
                f32x4 z = (f32x4){0.f, 0.f, 0.f, 0.f};
                z = __builtin_amdgcn_mfma_f32_16x16x32_bf16(kf[kb][0], qf0, z, 0, 0, 0);
                z = __builtin_amdgcn_mfma_f32_16x16x32_bf16(kf[kb][1], qf1, z, 0, 0, 0);
                sf[kb] = z;
            }

            if (kv0 + 63 > qbase) {               // causal mask
                const int qabs = qbase + lr;
#pragma unroll
                for (int kb = 0; kb < 4; ++kb)
#pragma unroll
                    for (int e = 0; e < 4; ++e) {
                        int kabs = kv0 + kb * 16 + lg * 4 + e;
                        if (kabs > qabs) sf[kb][e] = -1e30f;
                    }
            }

            float mb;
#pragma unroll
            for (int kb = 0; kb < 4; ++kb) {
                float t0 = fmaxf(fmaxf(sf[kb][0], sf[kb][1]), fmaxf(sf[kb][2], sf[kb][3]));
                mb = (kb == 0) ? t0 : fmaxf(mb, t0);
            }
            mb = fmaxf(mb, __shfl_xor(mb, 16));
            mb = fmaxf(mb, __shfl_xor(mb, 32));

            if (__any(mb > m)) {                  // defer-max
                float mn = fmaxf(m, mb);
                float sc = exp2f(m - mn);
                m = mn;
                l *= sc;
#pragma unroll
                for (int e = 0; e < 4; ++e) {
                    float sce = __shfl(sc, (lane & 48) | (lg * 4 + e));
#pragma unroll
                    for (int t = 0; t < 4; ++t) o[t][e] *= sce;
                }
            }

            float ssum = 0.f;
#pragma unroll
            for (int kb = 0; kb < 4; ++kb)
#pragma unroll
                for (int e = 0; e < 4; ++e) {
                    float pv = exp2f(sf[kb][e] - m);
                    sf[kb][e] = pv;
                    ssum += pv;
                }
            ssum += __shfl_xor(ssum, 16);
            ssum += __shfl_xor(ssum, 32);
            l += ssum;

            // pack P -> bf16, transpose through wave-local LDS
#pragma unroll
            for (int kb = 0; kb < 4; ++kb)
#pragma unroll
                for (int ps = 0; ps < 2; ++ps)
                    pwd[lr * 44 + kb * 8 + lg * 2 + ps] =
                        cvt_pk_bf16(sf[kb][2 * ps], sf[kb][2 * ps + 1]);

            asm volatile("s_waitcnt lgkmcnt(0)" ::: "memory");
            __builtin_amdgcn_sched_barrier(0);

            bf16x8 pa0 = load_bf16x8(pl + lr * 88 + lg * 8);
            bf16x8 pa1 = load_bf16x8(pl + lr * 88 + 32 + lg * 8);
#pragma unroll
            for (int t = 0; t < 4; ++t) {
                o[t] = __builtin_amdgcn_mfma_f32_16x16x32_bf16(pa0, vf[0][t], o[t], 0, 0, 0);
                o[t] = __builtin_amdgcn_mfma_f32_16x16x32_bf16(pa1, vf[1][t], o[t], 0, 0, 0);
            }
        }
    }

    // merge the pair (p=0, p=1) partials; overlay scratch on tile area
    __syncthreads();
    float* om  = (float*)(smem + qt * 4608);
    float* oml = om + 16 * 68;
    if (p == 1) {
#pragma unroll
        for (int t = 0; t < 4; ++t)
#pragma unroll
            for (int e = 0; e < 4; ++e)
                om[(lg * 4 + e) * 68 + t * 16 + lr] = o[t][e];
        if (lg == 0) { oml[lr] = m; oml[16 + lr] = l; }
    }
    __syncthreads();
    if (p == 0) {
        float m1 = oml[lr], l1 = oml[16 + lr];
        float ms = fmaxf(m, m1);
        float a0 = exp2f(m - ms), a1 = exp2f(m1 - ms);
        float inv = 1.f / (l * a0 + l1 * a1);
        a0 *= inv; a1 *= inv;
        float* ob = out + ((size_t)b * SEQ + qbase) * DHEAD;
#pragma unroll
        for (int e = 0; e < 4; ++e) {
            int src = (lane & 48) | (lg * 4 + e);
            float A0 = __shfl(a0, src);
            float A1 = __shfl(a1, src);
#pragma unroll
            for (int t = 0; t < 4; ++t) {
                float o1 = om[(lg * 4 + e) * 68 + t * 16 + lr];
                ob[(size_t)(lg * 4 + e) * DHEAD + t * 16 + lr] = o[t][e] * A0 + o1 * A1;
            }
        }
    }
}

extern "C" void kernel_launch(void* const* d_in, const int* in_sizes, int n_in,
                              void* d_out, int out_size, void* d_ws, size_t ws_size,
                              hipStream_t stream) {
    const float* x  = (const float*)d_in[0];
    const float* Wq = (const float*)d_in[1];
    const float* Wk = (const float*)d_in[2];
    const float* Wv = (const float*)d_in[3];
    float* out = (float*)d_out;

    char* ws = (char*)d_ws;
    unsigned short* WTf = (unsigned short*)(ws + WT_OFF);
    unsigned short* Q   = (unsigned short*)(ws + Q_OFF);
    unsigned short* K   = (unsigned short*)(ws + K_OFF);
    unsigned short* VT  = (unsigned short*)(ws + VT_OFF);

    hipLaunchKernelGGL(wtrans_kernel, dim3(96),  dim3(256), 0, stream, Wq, Wk, Wv, WTf);
    hipLaunchKernelGGL(proj_kernel,   dim3(512), dim3(256), 0, stream, x, WTf, Q, K, VT);
    hipLaunchKernelGGL(attn_kernel,   dim3(512), dim3(256), 0, stream, Q, K, VT, out);
}